// Round 2
// baseline (331.616 us; speedup 1.0000x reference)
//
#include <hip/hip_runtime.h>

// Inverse Haar 2D wavelet: in (16,12,512,512) f32 -> out (16,3,1024,1024) f32
// in viewed as (BC=48 groups) x (4 subbands A,Hh,V,D) x (512x512) planes.
// out[bc, 2h+0, 2w+0] = (A+Hh+V+D)*0.5
// out[bc, 2h+0, 2w+1] = (A+Hh-V-D)*0.5
// out[bc, 2h+1, 2w+0] = (A-Hh+V-D)*0.5
// out[bc, 2h+1, 2w+1] = (A-Hh-V+D)*0.5
//
// R2 layout (verified best): one thread owns 2 input columns (float2 per
// plane) -> exactly one float4 per output row. Loads are 8 B/lane contiguous
// (512 B/wave), stores 16 B/lane fully wave-contiguous (1024 B/instr).
//
// Round-1 change (re-run; round-1 bench died on container acquisition, not
// the kernel): NON-TEMPORAL stores. Output (192 MiB) is write-once/never-read;
// default stores allocate in L2/L3 and evict the 192 MiB input from the
// 256 MiB Infinity Cache between iterations, forcing HBM re-fetch of the
// input every run. `nt` stores stream the output to HBM without displacing
// the L3-resident input -> kernel FETCH_SIZE (HBM-only) should collapse once
// warm; reads come from L3 at >HBM bandwidth.

typedef float f32x4_t __attribute__((ext_vector_type(4)));

__global__ __launch_bounds__(256) void
witlayer_iwt_kernel(const float* __restrict__ in, float* __restrict__ out) {
    constexpr int W = 512;
    constexpr int W2 = W / 2;                    // 256 float2 per input row
    constexpr int PLANE = 512 * 512;             // 262144
    constexpr int OUT_PLANE = 1024 * 1024;       // 1048576
    constexpr int OUT_W = 1024;

    const int tid = blockIdx.x * blockDim.x + threadIdx.x;
    // total threads = 48 * 512 * 256 = 6,291,456
    const int f2 = tid & (W2 - 1);               // 8 bits: float2 index in row
    const int h  = (tid >> 8) & 511;             // 9 bits
    const int bc = tid >> 17;                    // 0..47

    const int in_off = h * W + f2 * 2;
    const float* base = in + (size_t)bc * 4 * PLANE + in_off;
    const float2 a  = *(const float2*)(base + 0 * PLANE);
    const float2 hh = *(const float2*)(base + 1 * PLANE);
    const float2 v  = *(const float2*)(base + 2 * PLANE);
    const float2 d  = *(const float2*)(base + 3 * PLANE);

    f32x4_t r0, r1;
    r0.x = (a.x + hh.x + v.x + d.x) * 0.5f;
    r0.y = (a.x + hh.x - v.x - d.x) * 0.5f;
    r0.z = (a.y + hh.y + v.y + d.y) * 0.5f;
    r0.w = (a.y + hh.y - v.y - d.y) * 0.5f;
    r1.x = (a.x - hh.x + v.x - d.x) * 0.5f;
    r1.y = (a.x - hh.x - v.x + d.x) * 0.5f;
    r1.z = (a.y - hh.y + v.y - d.y) * 0.5f;
    r1.w = (a.y - hh.y - v.y + d.y) * 0.5f;

    float* orow = out + (size_t)bc * OUT_PLANE + (size_t)(2 * h) * OUT_W;
    __builtin_nontemporal_store(r0, (f32x4_t*)orow + f2);           // row 2h
    __builtin_nontemporal_store(r1, (f32x4_t*)(orow + OUT_W) + f2); // row 2h+1
}

extern "C" void kernel_launch(void* const* d_in, const int* in_sizes, int n_in,
                              void* d_out, int out_size, void* d_ws, size_t ws_size,
                              hipStream_t stream) {
    const float* in = (const float*)d_in[0];
    float* out = (float*)d_out;
    const int total_threads = 48 * 512 * 256;    // 6,291,456
    const int block = 256;
    const int grid = total_threads / block;      // 24576
    witlayer_iwt_kernel<<<grid, block, 0, stream>>>(in, out);
}

// Round 3
// 325.513 us; speedup vs baseline: 1.0187x; 1.0187x over previous
//
#include <hip/hip_runtime.h>

// Inverse Haar 2D wavelet: in (16,12,512,512) f32 -> out (16,3,1024,1024) f32
// in viewed as (BC=48 groups) x (4 subbands A,Hh,V,D) x (512x512) planes.
// out[bc, 2h+0, 2w+0] = (A+Hh+V+D)*0.5
// out[bc, 2h+0, 2w+1] = (A+Hh-V-D)*0.5
// out[bc, 2h+1, 2w+0] = (A-Hh+V-D)*0.5
// out[bc, 2h+1, 2w+1] = (A-Hh-V+D)*0.5
//
// R2 layout (verified best): one thread owns 2 input columns (float2 per
// plane) -> exactly one float4 per output row. Loads are 8 B/lane contiguous
// (512 B/wave, full cache lines), stores 16 B/lane fully wave-contiguous
// (1024 B per store instruction).
//
// Round-2 post-mortem: __builtin_nontemporal_store REGRESSED (~+10-15 µs on
// the kernel portion; round-2 container had faster fills yet worse total).
// The L3-residency theory was wrong: the harness re-poison fill writes
// 768 MiB per dispatch between iterations, thrashing the entire 256 MiB
// Infinity Cache regardless of our store policy. nt bypassed L2 write
// combining for no benefit. REVERTED to plain stores (this round's single
// change). Do not reintroduce nt here.

__global__ __launch_bounds__(256) void
witlayer_iwt_kernel(const float* __restrict__ in, float* __restrict__ out) {
    constexpr int W = 512;
    constexpr int W2 = W / 2;                    // 256 float2 per input row
    constexpr int PLANE = 512 * 512;             // 262144
    constexpr int OUT_PLANE = 1024 * 1024;       // 1048576
    constexpr int OUT_W = 1024;

    const int tid = blockIdx.x * blockDim.x + threadIdx.x;
    // total threads = 48 * 512 * 256 = 6,291,456
    const int f2 = tid & (W2 - 1);               // 8 bits: float2 index in row
    const int h  = (tid >> 8) & 511;             // 9 bits
    const int bc = tid >> 17;                    // 0..47

    const int in_off = h * W + f2 * 2;
    const float* base = in + (size_t)bc * 4 * PLANE + in_off;
    const float2 a  = *(const float2*)(base + 0 * PLANE);
    const float2 hh = *(const float2*)(base + 1 * PLANE);
    const float2 v  = *(const float2*)(base + 2 * PLANE);
    const float2 d  = *(const float2*)(base + 3 * PLANE);

    float4 r0, r1;
    r0.x = (a.x + hh.x + v.x + d.x) * 0.5f;
    r0.y = (a.x + hh.x - v.x - d.x) * 0.5f;
    r0.z = (a.y + hh.y + v.y + d.y) * 0.5f;
    r0.w = (a.y + hh.y - v.y - d.y) * 0.5f;
    r1.x = (a.x - hh.x + v.x - d.x) * 0.5f;
    r1.y = (a.x - hh.x - v.x + d.x) * 0.5f;
    r1.z = (a.y - hh.y + v.y - d.y) * 0.5f;
    r1.w = (a.y - hh.y - v.y + d.y) * 0.5f;

    float* orow = out + (size_t)bc * OUT_PLANE + (size_t)(2 * h) * OUT_W;
    ((float4*)orow)[f2] = r0;                    // row 2h
    ((float4*)(orow + OUT_W))[f2] = r1;          // row 2h+1
}

extern "C" void kernel_launch(void* const* d_in, const int* in_sizes, int n_in,
                              void* d_out, int out_size, void* d_ws, size_t ws_size,
                              hipStream_t stream) {
    const float* in = (const float*)d_in[0];
    float* out = (float*)d_out;
    const int total_threads = 48 * 512 * 256;    // 6,291,456
    const int block = 256;
    const int grid = total_threads / block;      // 24576
    witlayer_iwt_kernel<<<grid, block, 0, stream>>>(in, out);
}